// Round 16
// baseline (125.394 us; speedup 1.0000x reference)
//
#include <hip/hip_runtime.h>

#define WINDOW   512
#define STEPSZ   256
#define NFRAMES  127
#define NSAMP    32768
#define NBATCH   512
#define NFREQ    256
#define BM       64
#define SAMP_TILE 16640          // 65 * 256 samples per tile
#define NPS      65

typedef __attribute__((ext_vector_type(8)))  short short8;   // 8 x bf16
typedef __attribute__((ext_vector_type(4)))  short bf16x4v;  // 4 x bf16
typedef __attribute__((ext_vector_type(16))) float f32x16;   // 32x32 MFMA acc
typedef __attribute__((ext_vector_type(4)))  float f4;

// Verified pattern (G4): spread row-bits (byte bits 9-11) into 16B-slot bits.
#define SWZ(byt) ((byt) ^ ((((byt) >> 9) & 7) << 4))

static __device__ __forceinline__ short f2bf(float x) {
    union { float f; unsigned u; } v; v.f = x;
    unsigned r = (v.u + 0x7fffu + ((v.u >> 16) & 1u)) >> 16;
    return (short)r;
}

// ---- kernel 1: normalize basis -> bf16 32x32-fragment-major layout --------
// Bf[(ns*32 + ks)*64 + (n&31) + 32*kg2][8] holds B[n][k = ks*16 + kg2*8 + j]
// (real n -> ns 0..7, imag -> ns 8..15). Proven since R10.
__global__ __launch_bounds__(256) void prep_kernel(const float* __restrict__ br,
                                                   const float* __restrict__ bi,
                                                   short* __restrict__ Bf) {
    const int lane = threadIdx.x & 63;
    const int wid  = threadIdx.x >> 6;
    const int n    = blockIdx.x * 4 + wid;          // freq 0..255
    const float* pr = br + (size_t)n * WINDOW + lane * 8;
    const float* pi = bi + (size_t)n * WINDOW + lane * 8;
    f4 r0 = *(const f4*)pr;
    f4 r1 = *(const f4*)(pr + 4);
    f4 i0 = *(const f4*)pi;
    f4 i1 = *(const f4*)(pi + 4);
    float ss = 0.f;
#pragma unroll
    for (int j = 0; j < 4; ++j)
        ss += r0[j]*r0[j] + r1[j]*r1[j] + i0[j]*i0[j] + i1[j]*i1[j];
#pragma unroll
    for (int d = 1; d < 64; d <<= 1) ss += __shfl_xor(ss, d, 64);
    const float inv = 1.0f / (sqrtf(ss) + 1e-8f);
    short8 hr, hi;
#pragma unroll
    for (int j = 0; j < 4; ++j) {
        hr[j]     = f2bf(r0[j] * inv);
        hr[j + 4] = f2bf(r1[j] * inv);
        hi[j]     = f2bf(i0[j] * inv);
        hi[j + 4] = f2bf(i1[j] * inv);
    }
    const int ks  = lane >> 1, kg2 = lane & 1;
    const int nsR = n >> 5;
    const int nsI = 8 + (n >> 5);
    const int sl  = (n & 31) + 32 * kg2;
    *(short8*)(Bf + ((size_t)(nsR * 32 + ks) * 64 + sl) * 8) = hr;
    *(short8*)(Bf + ((size_t)(nsI * 32 + ks) * 64 + sl) * 8) = hi;
}

// ---- kernel 2: fused norms + bf16 32x32x16 MFMA GEMM, 8 waves/SIMD ---------
// grid = 512 b * 2 m-halves = 1024 blocks; 1024 thr (16 waves).
// Wave = 2 m-supers x 1 n-super: acc[2][1] = 32 AGPR -> total regs <= 64 ->
// 2 blocks/CU = 32 waves/CU = 8 waves/SIMD. TLP hides L2/LDS/store latency
// that 4-waves/SIMD geometries could not. n is wave-uniform (no epilogue
// divergence). Staging uses 1 live f4 (reg-budget discipline).
__global__ __launch_bounds__(1024, 8) void mel_kernel(const float* __restrict__ audio,
                                                      const short* __restrict__ Bf,
                                                      float* __restrict__ out) {
    __shared__ short smp[SAMP_TILE];   // 33280 B, swizzled bf16 samples
    __shared__ float ps[NPS];
    __shared__ float invn[BM];

    const int tid  = threadIdx.x;
    const int lane = tid & 63;
    const int wid  = tid >> 6;          // 0..15 = n-super

    const int b  = blockIdx.x >> 1;
    const int mh = blockIdx.x & 1;
    const int f0 = mh * BM;

    float* out_norms = out;
    float* out_real  = out + 65024;
    float* out_imag  = out + 65024 + 16646144;

    const float* abase = audio + (size_t)b * NSAMP + f0 * STEPSZ;
    const int smax = NSAMP - f0 * STEPSZ - 4;

    const int rl32 = lane & 31;
    const int kg2  = lane >> 5;

    // ---- Phase 1: stream 4 samples/thread/iter (1 live f4) + norm partials ----
#pragma unroll
    for (int it = 0; it < 5; ++it) {
        const int sl = it * 4096 + tid * 4;
        float ss = 0.f;
        if (sl < SAMP_TILE) {
            const int slc = sl < smax ? sl : smax;
            f4 v = *(const f4*)(abase + slc);
            bf16x4v h;
#pragma unroll
            for (int q = 0; q < 4; ++q) {
                ss += v[q] * v[q];
                h[q] = f2bf(v[q]);
            }
            *(bf16x4v*)((char*)smp + SWZ(sl * 2)) = h;
        }
        ss += __shfl_xor(ss, 1, 64);
        ss += __shfl_xor(ss, 2, 64);
        ss += __shfl_xor(ss, 4, 64);
        ss += __shfl_xor(ss, 8, 64);
        ss += __shfl_xor(ss, 16, 64);
        ss += __shfl_xor(ss, 32, 64);   // 64 lanes span 256 samples here
        const int chunk = (it * 4096 + tid * 4) >> 8;
        if ((tid & 63) == 0 && chunk < NPS) ps[chunk] = ss;
    }
    __syncthreads();

    // ---- norms: frame f covers chunks f, f+1 ----
    if (tid < BM) {
        const float nrm = sqrtf(ps[tid] + ps[tid + 1]);
        const int fr = f0 + tid;
        if (fr < NFRAMES) out_norms[b * NFRAMES + fr] = nrm;
        invn[tid] = 1.0f / (nrm + 1e-8f);
    }
    __syncthreads();

    // ---- Phase 2: K-loop (32 steps of k=16), wave = 2 MFMA/step ----
    const int rb0 = (0 * 32 + rl32) * 512 + kg2 * 16;
    const int rb1 = (1 * 32 + rl32) * 512 + kg2 * 16;
    const int X0  = (rl32 & 7) << 4;
    const int X1  = ((rl32 + 1) & 7) << 4;
    const char* sb = (const char*)smp;

    const short* bp = Bf + ((size_t)wid * 32 * 64 + lane) * 8;

    // even/odd depth-2 B prefetch (8 VGPR)
    short8 eb = *(const short8*)bp;
    short8 ob = *(const short8*)(bp + 512);

    f32x16 acc0 = (f32x16)0.f;
    f32x16 acc1 = (f32x16)0.f;

#pragma unroll
    for (int ks = 0; ks < 32; ++ks) {
        const int X  = (ks < 16) ? X0 : X1;
        const int kb = ks * 32;
        short8 a0 = *(const short8*)(sb + ((rb0 + kb) ^ X));
        short8 a1 = *(const short8*)(sb + ((rb1 + kb) ^ X));
        short8 cb;
        if ((ks & 1) == 0) {
            cb = eb;
            if (ks < 30) eb = *(const short8*)(bp + (size_t)(ks + 2) * 512);
        } else {
            cb = ob;
            if (ks < 30) ob = *(const short8*)(bp + (size_t)(ks + 2) * 512);
        }
        acc0 = __builtin_amdgcn_mfma_f32_32x32x16_bf16(a0, cb, acc0, 0, 0, 0);
        acc1 = __builtin_amdgcn_mfma_f32_32x32x16_bf16(a1, cb, acc1, 0, 0, 0);
    }

    // ---- Epilogue: C/D map col=lane&31, row=(reg&3)+8*(reg>>2)+4*(lane>>5) ----
    const int n    = wid * 32 + rl32;               // wave-uniform real/imag
    float* dst     = (n < NFREQ) ? out_real : out_imag;
    const int kcol = n & (NFREQ - 1);
#pragma unroll
    for (int mi = 0; mi < 2; ++mi) {
        const f32x16 a = mi ? acc1 : acc0;
        const int rbase = mi * 32 + 4 * kg2;
#pragma unroll
        for (int r = 0; r < 16; ++r) {
            const int rr = rbase + (r & 3) + 8 * (r >> 2);
            const int fr = f0 + rr;
            if (fr < NFRAMES)
                dst[((size_t)b * NFRAMES + fr) * NFREQ + kcol] = a[r] * invn[rr];
        }
    }
}

extern "C" void kernel_launch(void* const* d_in, const int* in_sizes, int n_in,
                              void* d_out, int out_size, void* d_ws, size_t ws_size,
                              hipStream_t stream) {
    const float* audio = (const float*)d_in[0];
    const float* br    = (const float*)d_in[1];
    const float* bi    = (const float*)d_in[2];
    float* out = (float*)d_out;
    short* Bf  = (short*)d_ws;               // 512x512 bf16 = 512 KiB

    prep_kernel<<<64, 256, 0, stream>>>(br, bi, Bf);
    mel_kernel<<<NBATCH * 2, 1024, 0, stream>>>(audio, Bf, out);
}

// Round 17
// 117.396 us; speedup vs baseline: 1.0681x; 1.0681x over previous
//
#include <hip/hip_runtime.h>

#define WINDOW   512
#define STEPSZ   256
#define NFRAMES  127
#define NSAMP    32768
#define NBATCH   512
#define NFREQ    256
#define BM       64
#define SAMP_TILE 16640          // 65 * 256 samples per half-batch tile
#define NPS      65

typedef __attribute__((ext_vector_type(8)))  short short8;   // 8 x bf16
typedef __attribute__((ext_vector_type(4)))  short bf16x4v;  // 4 x bf16
typedef __attribute__((ext_vector_type(16))) float f32x16;   // 32x32 MFMA acc
typedef __attribute__((ext_vector_type(4)))  float f4;

// Verified pattern (G4): spread row-bits (byte bits 9-11) into 16B-slot bits.
#define SWZ(byt) ((byt) ^ ((((byt) >> 9) & 7) << 4))

static __device__ __forceinline__ short f2bf(float x) {
    union { float f; unsigned u; } v; v.f = x;
    unsigned r = (v.u + 0x7fffu + ((v.u >> 16) & 1u)) >> 16;
    return (short)r;
}

// ---- kernel 1: normalize basis -> bf16 32x32-fragment-major layout --------
// Bf[(ns*32 + ks)*64 + (n&31) + 32*kg2][8] holds B[n][k = ks*16 + kg2*8 + j]
// (real n -> ns 0..7, imag -> ns 8..15). Proven since R10.
__global__ __launch_bounds__(256) void prep_kernel(const float* __restrict__ br,
                                                   const float* __restrict__ bi,
                                                   short* __restrict__ Bf) {
    const int lane = threadIdx.x & 63;
    const int wid  = threadIdx.x >> 6;
    const int n    = blockIdx.x * 4 + wid;          // freq 0..255
    const float* pr = br + (size_t)n * WINDOW + lane * 8;
    const float* pi = bi + (size_t)n * WINDOW + lane * 8;
    f4 r0 = *(const f4*)pr;
    f4 r1 = *(const f4*)(pr + 4);
    f4 i0 = *(const f4*)pi;
    f4 i1 = *(const f4*)(pi + 4);
    float ss = 0.f;
#pragma unroll
    for (int j = 0; j < 4; ++j)
        ss += r0[j]*r0[j] + r1[j]*r1[j] + i0[j]*i0[j] + i1[j]*i1[j];
#pragma unroll
    for (int d = 1; d < 64; d <<= 1) ss += __shfl_xor(ss, d, 64);
    const float inv = 1.0f / (sqrtf(ss) + 1e-8f);
    short8 hr, hi;
#pragma unroll
    for (int j = 0; j < 4; ++j) {
        hr[j]     = f2bf(r0[j] * inv);
        hr[j + 4] = f2bf(r1[j] * inv);
        hi[j]     = f2bf(i0[j] * inv);
        hi[j + 4] = f2bf(i1[j] * inv);
    }
    const int ks  = lane >> 1, kg2 = lane & 1;
    const int nsR = n >> 5;
    const int nsI = 8 + (n >> 5);
    const int sl  = (n & 31) + 32 * kg2;
    *(short8*)(Bf + ((size_t)(nsR * 32 + ks) * 64 + sl) * 8) = hr;
    *(short8*)(Bf + ((size_t)(nsI * 32 + ks) * 64 + sl) * 8) = hi;
}

// Staging macros (tile 1), T14 split: loads held in named regs through K(0).
#define SLD(IT, SV)                                                       \
    {                                                                     \
        const int sl = (IT) * 4096 + tid * 4;                             \
        if (sl < SAMP_TILE) {                                             \
            const int slc = sl < 16380 ? sl : 16380;                      \
            SV = *(const f4*)(abase1 + slc);                              \
        }                                                                 \
    }

#define STWR(IT, SV)                                                      \
    {                                                                     \
        const int sl = (IT) * 4096 + tid * 4;                             \
        float ss = 0.f;                                                   \
        if (sl < SAMP_TILE) {                                             \
            bf16x4v h;                                                    \
            _Pragma("unroll")                                             \
            for (int q = 0; q < 4; ++q) {                                 \
                ss += SV[q] * SV[q];                                      \
                h[q] = f2bf(SV[q]);                                       \
            }                                                             \
            *(bf16x4v*)((char*)smp[1] + SWZ(sl * 2)) = h;                 \
        }                                                                 \
        ss += __shfl_xor(ss, 1, 64);                                      \
        ss += __shfl_xor(ss, 2, 64);                                      \
        ss += __shfl_xor(ss, 4, 64);                                      \
        ss += __shfl_xor(ss, 8, 64);                                      \
        ss += __shfl_xor(ss, 16, 64);                                     \
        ss += __shfl_xor(ss, 32, 64);                                     \
        if ((tid & 63) == 0 && ((IT) * 4096 + tid * 4) < SAMP_TILE)       \
            ps[1][((IT) * 4096 + tid * 4) >> 8] = ss;                     \
    }

// ---- kernel 2: dbuf-pipelined fused norms + bf16 32x32x16 MFMA GEMM --------
// grid = 512 (block = 1 batch, 2 half-tiles); 1024 thr (16 waves, 1m x 16n).
// Wave = 2m-supers x 1n-super: acc[2][1] = 32 AGPR. Freed regs fund the
// pipeline: stage-LOAD(tile1) before K(0) (HBM latency under MFMA),
// stage-WRITE after K(0); one barrier per tile; stores(t) overlap K(t+1).
__global__ __launch_bounds__(1024, 4) void mel_kernel(const float* __restrict__ audio,
                                                      const short* __restrict__ Bf,
                                                      float* __restrict__ out) {
    __shared__ short smp[2][SAMP_TILE];   // 2 x 33280 B, swizzled bf16
    __shared__ float ps[2][NPS + 1];

    const int tid  = threadIdx.x;
    const int lane = tid & 63;
    const int wid  = tid >> 6;          // 0..15 = n-super

    const int b = blockIdx.x;

    float* out_norms = out;
    float* out_real  = out + 65024;
    float* out_imag  = out + 65024 + 16646144;

    const int rl32 = lane & 31;
    const int kg2  = lane >> 5;

    const short* bp = Bf + ((size_t)wid * 32 * 64 + lane) * 8;
    const int rb0 = rl32 * 512 + kg2 * 16;
    const int rb1 = (32 + rl32) * 512 + kg2 * 16;
    const int X0  = (rl32 & 7) << 4;
    const int X1  = ((rl32 + 1) & 7) << 4;

    // ---- prologue: stage tile 0 (samples 0..16640) ----
    {
        const float* abase = audio + (size_t)b * NSAMP;
#pragma unroll
        for (int it = 0; it < 5; ++it) {
            const int sl = it * 4096 + tid * 4;
            float ss = 0.f;
            if (sl < SAMP_TILE) {
                f4 v = *(const f4*)(abase + sl);
                bf16x4v h;
#pragma unroll
                for (int q = 0; q < 4; ++q) {
                    ss += v[q] * v[q];
                    h[q] = f2bf(v[q]);
                }
                *(bf16x4v*)((char*)smp[0] + SWZ(sl * 2)) = h;
            }
            ss += __shfl_xor(ss, 1, 64);
            ss += __shfl_xor(ss, 2, 64);
            ss += __shfl_xor(ss, 4, 64);
            ss += __shfl_xor(ss, 8, 64);
            ss += __shfl_xor(ss, 16, 64);
            ss += __shfl_xor(ss, 32, 64);
            if ((tid & 63) == 0 && sl < SAMP_TILE) ps[0][sl >> 8] = ss;
        }
    }
    __syncthreads();

    const float* abase1 = audio + (size_t)b * NSAMP + 16384;

#pragma unroll
    for (int t = 0; t < 2; ++t) {
        const int f0 = t * BM;
        const char* sb = (const char*)smp[t];

        // ---- stage-LOAD tile 1 (held in regs through K(0)) ----
        f4 sv0, sv1, sv2, sv3, sv4;
        if (t == 0) {
            SLD(0, sv0) SLD(1, sv1) SLD(2, sv2) SLD(3, sv3) SLD(4, sv4)
        }

        // even/odd depth-2 B prefetch
        short8 eb = *(const short8*)bp;
        short8 ob = *(const short8*)(bp + 512);

        f32x16 acc0 = (f32x16)0.f;
        f32x16 acc1 = (f32x16)0.f;

        // ---- K-loop (32 steps of k=16), wave = 2 MFMA/step ----
#pragma unroll
        for (int ks = 0; ks < 32; ++ks) {
            const int X  = (ks < 16) ? X0 : X1;
            const int kb = ks * 32;
            short8 a0 = *(const short8*)(sb + ((rb0 + kb) ^ X));
            short8 a1 = *(const short8*)(sb + ((rb1 + kb) ^ X));
            short8 cb;
            if ((ks & 1) == 0) {
                cb = eb;
                if (ks < 30) eb = *(const short8*)(bp + (size_t)(ks + 2) * 512);
            } else {
                cb = ob;
                if (ks < 30) ob = *(const short8*)(bp + (size_t)(ks + 2) * 512);
            }
            acc0 = __builtin_amdgcn_mfma_f32_32x32x16_bf16(a0, cb, acc0, 0, 0, 0);
            acc1 = __builtin_amdgcn_mfma_f32_32x32x16_bf16(a1, cb, acc1, 0, 0, 0);
        }

        // ---- stage-WRITE tile 1 (cvt + swizzled LDS + fused ss reduce) ----
        if (t == 0) {
            STWR(0, sv0) STWR(1, sv1) STWR(2, sv2) STWR(3, sv3) STWR(4, sv4)
        }

        __syncthreads();   // ps[t] visible; tile-1 LDS complete; K(t) done

        // ---- epilogue tile t: norms + scaled stores (overlap K(t+1)) ----
        if (tid < BM) {
            const int fr = f0 + tid;
            if (fr < NFRAMES)
                out_norms[b * NFRAMES + fr] = sqrtf(ps[t][tid] + ps[t][tid + 1]);
        }

        const int n    = wid * 32 + rl32;           // wave-uniform real/imag
        float* dst     = (n < NFREQ) ? out_real : out_imag;
        const int kcol = n & (NFREQ - 1);
#pragma unroll
        for (int mi = 0; mi < 2; ++mi) {
            const f32x16 a = mi ? acc1 : acc0;
            const int rbase = mi * 32 + 4 * kg2;
#pragma unroll
            for (int r = 0; r < 16; ++r) {
                const int rr = rbase + (r & 3) + 8 * (r >> 2);
                const int fr = f0 + rr;
                if (fr < NFRAMES) {
                    const float iv = 1.0f / (sqrtf(ps[t][rr] + ps[t][rr + 1]) + 1e-8f);
                    dst[((size_t)b * NFRAMES + fr) * NFREQ + kcol] = a[r] * iv;
                }
            }
        }
    }
}

extern "C" void kernel_launch(void* const* d_in, const int* in_sizes, int n_in,
                              void* d_out, int out_size, void* d_ws, size_t ws_size,
                              hipStream_t stream) {
    const float* audio = (const float*)d_in[0];
    const float* br    = (const float*)d_in[1];
    const float* bi    = (const float*)d_in[2];
    float* out = (float*)d_out;
    short* Bf  = (short*)d_ws;               // 512x512 bf16 = 512 KiB

    prep_kernel<<<64, 256, 0, stream>>>(br, bi, Bf);
    mel_kernel<<<NBATCH, 1024, 0, stream>>>(audio, Bf, out);
}